// Round 13
// baseline (326.535 us; speedup 1.0000x reference)
//
#include <hip/hip_runtime.h>

namespace {

typedef __attribute__((ext_vector_type(8))) short short8;   // MFMA A/B frag (8 bf16)
typedef __attribute__((ext_vector_type(4))) float floatx4;  // MFMA C/D frag

constexpr int T    = 512;
constexpr int H    = 64;
constexpr int TPB  = 256;   // 4 waves/block
constexpr int MB   = 4;     // grid 512 -> 2 INDEPENDENT blocks/CU (decoupled barriers)
constexpr int HST  = 72;    // ushorts per (bat,type) h-row: 64 data + 8 pad (rows stagger 4 banks)
constexpr int XSTR = 516;   // xs row stride (floats)
constexpr int FSTR = 68;    // hf32 row stride (floats, head only)

constexpr int DPP_ROR8 = 0x128;  // row_ror:8 -> lane i reads lane i^8 (within row of 16)

__device__ __forceinline__ ushort f2bf(float x) {  // fp32 -> bf16 RN-even (finite)
  unsigned u = __float_as_uint(x);
  unsigned r = u + 0x7fffu + ((u >> 16) & 1u);
  return (ushort)(r >> 16);
}
__device__ __forceinline__ float bf2f(ushort h) {
  return __uint_as_float(((unsigned)h) << 16);
}
__device__ __forceinline__ float fsig(float x) {
  return __builtin_amdgcn_rcpf(1.0f + __expf(-x));
}
__device__ __forceinline__ float ftanh(float x) {
  return fmaf(-2.0f, __builtin_amdgcn_rcpf(1.0f + __expf(2.0f * x)), 1.0f);
}
__device__ __forceinline__ float swz8(float v) {   // value from lane^8 (row of 16), VALU pipe
  return __int_as_float(__builtin_amdgcn_update_dpp(
      0, __float_as_int(v), DPP_ROR8, 0xf, 0xf, true));
}

// R13: R12's gate-interleaved machinery at MB=4 with 2 decoupled blocks/CU.
//   B cols: col n -> batch n&3, quadrant q=n>>2; type = q>>1 (cols duplicate
//   pairwise: lanes n and n^4 read the same LDS row -> broadcast, free).
//   Wave wj computes its 4 tiles gt=4wj+tt over all cols (16 MFMA: per tile
//   d1 = Whi x B (K=64, 2 MFMA), d2 = Wlo x B (2 MFMA)).
//   A-row permutation (verified R12): A row m of tile gt loads W_hh row
//   64*(m&3) + 4*gt + (m>>2)  =>  D reg j of lane (n,kg) = gate j of unit
//   4*gt+kg. Lane owns tile q (local): unit u = 16wj + 4q + kg, batch n&3 —
//   64 distinct states/wave, 256/block = 64 units x 4 batches. 1 c-state/lane.
//   Exchange (partner lane^8 has same bat, flipped type, tile q^2):
//     own = s[q], snd = s[q^2];  p = own + swz8(snd) + pinit   (4-term split).
//   h store: separate (bat,type) rows; trunc-split (hi = truncate to bf16,
//   lo = RN(hk - hi): remainder exact, same total accuracy, fewer ops).
__global__ __launch_bounds__(TPB, 2)
void lstm_mfma(const float* __restrict__ xg,
               const float* __restrict__ W_ih,
               const float* __restrict__ W_hh,
               const float* __restrict__ b_ih,
               const float* __restrict__ b_hh,
               const float* __restrict__ fc1_w,
               const float* __restrict__ fc1_b,
               const float* __restrict__ fc2_w,
               const float* __restrict__ fc2_b,
               float* __restrict__ out)
{
  __shared__ __align__(16) ushort hA[8 * HST];    // h double-buffer: 8 rows (bat,type)
  __shared__ __align__(16) ushort hB[8 * HST];
  __shared__ __align__(16) float  xs[MB * XSTR];
  __shared__ __align__(16) float  hf[MB * FSTR];  // final h fp32 (head; written once)
  __shared__ float zs[MB][16];

  const int tid  = threadIdx.x;
  const int b0   = blockIdx.x * MB;
  const int lane = tid & 63;
  const int wj   = tid >> 6;       // wave 0..3 -> tiles {4wj..4wj+3}
  const int n    = lane & 15;      // MFMA col
  const int kg   = lane >> 4;      // k-group (A/B), row-quad (D)
  const int bat  = n & 3;
  const int q    = n >> 2;         // quadrant 0..3; type = q>>1
  const bool q1  = (q & 1) != 0;
  const bool q2  = (q & 2) != 0;

  // ---- stage x (coalesced float4) ----
  for (int i = tid; i < MB * T / 4; i += TPB) {
    const int xb = i >> 7, tq = i & 127;
    float4 v = ((const float4*)(xg + (size_t)(b0 + xb) * T))[tq];
    *(float4*)&xs[xb * XSTR + tq * 4] = v;
  }
  // ---- zero h buffers (h0 = 0; pads stay 0) ----
  for (int i = tid; i < 8 * HST; i += TPB) { hA[i] = 0; hB[i] = 0; }

  // ---- A-frags for 4 tiles (gate-interleaved row permutation, verified R12) ----
  short8 whi[4][2], wlo[4][2];     // [tile][k-half]
#pragma unroll
  for (int tt = 0; tt < 4; ++tt) {
    const int gt   = 4 * wj + tt;
    const int arow = 64 * (n & 3) + 4 * gt + (n >> 2);  // gate n&3, local unit n>>2
    const float* wr = W_hh + arow * H + 8 * kg;
    const float4 p0 = *(const float4*)(wr + 0);
    const float4 p1 = *(const float4*)(wr + 4);
    const float4 p2 = *(const float4*)(wr + 32);
    const float4 p3 = *(const float4*)(wr + 36);
    const float v0[8] = {p0.x, p0.y, p0.z, p0.w, p1.x, p1.y, p1.z, p1.w};
    const float v1[8] = {p2.x, p2.y, p2.z, p2.w, p3.x, p3.y, p3.z, p3.w};
#pragma unroll
    for (int j = 0; j < 8; ++j) {
      const ushort h0 = f2bf(v0[j]);
      whi[tt][0][j] = (short)h0;
      wlo[tt][0][j] = (short)f2bf(v0[j] - bf2f(h0));   // exact remainder, then RN
      const ushort h1 = f2bf(v1[j]);
      whi[tt][1][j] = (short)h1;
      wlo[tt][1][j] = (short)f2bf(v1[j] - bf2f(h1));
    }
  }

  // ---- owned c-state: unit u, batch bat ----
  const int u = 16 * wj + 4 * q + kg;
  float bia[4], wih[4];
#pragma unroll
  for (int j = 0; j < 4; ++j) {                 // gate rows: i,f,g,o = 64j + u
    const int row = 64 * j + u;
    bia[j] = b_ih[row] + b_hh[row];
    wih[j] = W_ih[row];
  }

  const int rdoff = (2 * bat + (q >> 1)) * HST + 8 * kg;  // my col's (bat,type) row
  const int whi_o = (2 * bat + 0) * HST + u;              // h hi write
  const int wlo_o = (2 * bat + 1) * HST + u;              // h lo write
  const float* xq = &xs[bat * XSTR];
  float c = 0.0f, hk = 0.0f;

  __syncthreads();

#define STEP(HR, HW, TT)                                                       \
  {                                                                            \
    const ushort* hb = (HR) + rdoff;                                           \
    const short8 f0 = *(const short8*)(hb + 0);    /* k 0..31  (my type) */    \
    const short8 f1 = *(const short8*)(hb + 32);   /* k 32..63 */              \
    const floatx4 zf = {0.f, 0.f, 0.f, 0.f};                                   \
    floatx4 d1[4], d2[4];                                                      \
    _Pragma("unroll") for (int tt = 0; tt < 4; ++tt) {                         \
      d1[tt] = __builtin_amdgcn_mfma_f32_16x16x32_bf16(whi[tt][0], f0, zf, 0, 0, 0); \
      d2[tt] = __builtin_amdgcn_mfma_f32_16x16x32_bf16(wlo[tt][0], f0, zf, 0, 0, 0); \
    }                                                                          \
    _Pragma("unroll") for (int tt = 0; tt < 4; ++tt) {                         \
      d1[tt] = __builtin_amdgcn_mfma_f32_16x16x32_bf16(whi[tt][1], f1, d1[tt], 0, 0, 0); \
      d2[tt] = __builtin_amdgcn_mfma_f32_16x16x32_bf16(wlo[tt][1], f1, d2[tt], 0, 0, 0); \
    }                                                                          \
    const float xt = xq[(TT)];                                                 \
    float pinit[4];                                                            \
    _Pragma("unroll") for (int j = 0; j < 4; ++j)                              \
      pinit[j] = fmaf(xt, wih[j], bia[j]);                                     \
    float p[4];                                                                \
    _Pragma("unroll") for (int j = 0; j < 4; ++j) {                            \
      const float s0 = d1[0][j] + d2[0][j];                                    \
      const float s1 = d1[1][j] + d2[1][j];                                    \
      const float s2 = d1[2][j] + d2[2][j];                                    \
      const float s3 = d1[3][j] + d2[3][j];                                    \
      const float tl = q1 ? s1 : s0;                                           \
      const float th = q1 ? s3 : s2;                                           \
      const float own = q2 ? th : tl;                                          \
      const float snd = q2 ? tl : th;    /* partner's tile, my col type */     \
      p[j] = own + swz8(snd) + pinit[j];                                       \
    }                                                                          \
    const float ig = fsig(p[0]);                                               \
    const float fg = fsig(p[1]);                                               \
    const float gc = ftanh(p[2]);                                              \
    const float og = fsig(p[3]);                                               \
    c  = fmaf(fg, c, ig * gc);                                                 \
    hk = og * ftanh(c);                                                        \
    const ushort hib = (ushort)(__float_as_uint(hk) >> 16);  /* trunc split */ \
    (HW)[whi_o] = hib;                                                         \
    (HW)[wlo_o] = f2bf(hk - bf2f(hib));    /* remainder exact, RN to bf16 */   \
    __syncthreads();                                                           \
  }

  for (int t = 0; t < T; t += 2) {
    STEP(hA, hB, t);
    STEP(hB, hA, t + 1);
  }
#undef STEP

  // ---- final h (fp32, from registers) -> LDS once; then the head ----
  hf[bat * FSTR + u] = hk;
  __syncthreads();
  if (tid < MB * 16) {
    const int bq = tid >> 4, j2 = tid & 15;   // 4 batches x 16 hidden2
    float s = fc1_b[j2];
    const float* fw = fc1_w + j2 * H;
#pragma unroll
    for (int k = 0; k < H; ++k) s = fmaf(hf[bq * FSTR + k], fw[k], s);
    s = fmaxf(s, 0.0f);
    zs[bq][j2] = s * fc2_w[j2];
  }
  __syncthreads();
  if (tid < MB) {
    float s = fc2_b[0];
#pragma unroll
    for (int j = 0; j < 16; ++j) s += zs[tid][j];
    out[b0 + tid] = s;
  }
}

}  // namespace

extern "C" void kernel_launch(void* const* d_in, const int* in_sizes, int n_in,
                              void* d_out, int out_size, void* d_ws, size_t ws_size,
                              hipStream_t stream) {
  const float* xg    = (const float*)d_in[0];
  const float* W_ih  = (const float*)d_in[1];
  const float* W_hh  = (const float*)d_in[2];
  const float* b_ih  = (const float*)d_in[3];
  const float* b_hh  = (const float*)d_in[4];
  const float* fc1_w = (const float*)d_in[5];
  const float* fc1_b = (const float*)d_in[6];
  const float* fc2_w = (const float*)d_in[7];
  const float* fc2_b = (const float*)d_in[8];
  float* out = (float*)d_out;

  dim3 grid(2048 / MB);   // 512 blocks -> 2 independent blocks/CU
  dim3 block(TPB);
  hipLaunchKernelGGL(lstm_mfma, grid, block, 0, stream,
                     xg, W_ih, W_hh, b_ih, b_hh, fc1_w, fc1_b, fc2_w, fc2_b, out);
}